// Round 1
// baseline (677.560 us; speedup 1.0000x reference)
//
#include <hip/hip_runtime.h>

typedef __attribute__((ext_vector_type(8))) short bf16x8;
typedef __attribute__((ext_vector_type(4))) float f32x4;
typedef __attribute__((ext_vector_type(4))) unsigned short u16x4;

#define BM 128
#define BN 128
#define BK 64

// ---------- exact power of two: 2^e for e in [-127, 127] ----------
__device__ __forceinline__ float pow2i(int e) {
  if (e >= -126) return __uint_as_float((unsigned)(e + 127) << 23);
  return __uint_as_float(0x00400000u >> (-126 - e)); // e == -127 -> 2^-127 subnormal
}

// ---------- emulate round-to-nearest-even cast to e4m3fn (saturating), then dequant ----------
__device__ __forceinline__ float qdq_e4m3(float x, float inv, float scale) {
  float s = x * inv;            // exact: inv is a power of two
  float a = fabsf(s);
  int ee = (int)((__float_as_uint(a) >> 23) & 0xffu) - 127;  // floor(log2(a)) for normals
  ee = ee < -6 ? -6 : (ee > 8 ? 8 : ee);                     // clamp to e4m3 binades
  float istep = __uint_as_float((unsigned)(130 - ee) << 23); // 2^(3-ee)
  float step  = __uint_as_float((unsigned)(124 + ee) << 23); // 2^(ee-3)
  float q = rintf(a * istep) * step;  // RNE, matches jnp.round
  q = fminf(q, 448.0f);               // saturate (e4m3fn has no inf)
  return copysignf(q, s) * scale;     // exact in bf16 (<=4 significant bits * 2^k)
}

// ---------- MX quant+dequant: fp32 in, bf16 out; 32-elem blocks share E8M0 scale ----------
// 8 consecutive lanes (each holding a float4) cover one 32-element block.
__global__ void quant_mx(const float4* __restrict__ in, u16x4* __restrict__ outq,
                         long long n4) {
  long long idx = (long long)blockIdx.x * blockDim.x + threadIdx.x;
  long long stride = (long long)gridDim.x * blockDim.x;
  for (; idx < n4; idx += stride) {
    float4 v = in[idx];
    float am = fmaxf(fmaxf(fabsf(v.x), fabsf(v.y)), fmaxf(fabsf(v.z), fabsf(v.w)));
    am = fmaxf(am, __shfl_xor(am, 1));
    am = fmaxf(am, __shfl_xor(am, 2));
    am = fmaxf(am, __shfl_xor(am, 4));
    // E8M0 scale exponent: floor(log2(amax)) - 8, clamped to [-127, 127]
    int e = (int)((__float_as_uint(am) >> 23) & 0xffu) - 135; // -127 - 8
    e = e < -127 ? -127 : (e > 127 ? 127 : e);
    float scale = pow2i(e);
    float inv   = pow2i(-e);
    float r0 = qdq_e4m3(v.x, inv, scale);
    float r1 = qdq_e4m3(v.y, inv, scale);
    float r2 = qdq_e4m3(v.z, inv, scale);
    float r3 = qdq_e4m3(v.w, inv, scale);
    u16x4 o;
    o[0] = (unsigned short)(__float_as_uint(r0) >> 16); // exact truncation: low bits are 0
    o[1] = (unsigned short)(__float_as_uint(r1) >> 16);
    o[2] = (unsigned short)(__float_as_uint(r2) >> 16);
    o[3] = (unsigned short)(__float_as_uint(r3) >> 16);
    outq[idx] = o;
  }
}

// ---------- async global -> LDS, 16B per lane ----------
__device__ __forceinline__ void gload_lds16(const void* g, void* l) {
  __builtin_amdgcn_global_load_lds(
      (const __attribute__((address_space(1))) unsigned int*)g,
      (__attribute__((address_space(3))) unsigned int*)l, 16, 0, 0);
}

// ---------- bf16 MFMA GEMM: C[M,N] = A[M,K] * B[N,K]^T + bias ----------
__global__ __launch_bounds__(256) void gemm_mx(
    const unsigned short* __restrict__ A, const unsigned short* __restrict__ B,
    const float* __restrict__ bias, float* __restrict__ C,
    int M, int N, int K) {
  __shared__ __align__(16) unsigned short As[BM * BK];
  __shared__ __align__(16) unsigned short Bs[BN * BK];

  const int tid = threadIdx.x;
  const int l = tid & 63;
  const int w = tid >> 6;
  const int wr = w >> 1;   // 2x2 wave grid over the 128x128 tile
  const int wc = w & 1;

  // XCD-aware bijective swizzle (grid % 8 == 0 here)
  const int nbx = N / BN;
  const int bid = blockIdx.x;
  const int cpx = gridDim.x >> 3;
  const int swz = (bid & 7) * cpx + (bid >> 3);
  const int by = swz / nbx, bx = swz % nbx;

  const size_t baseA = (size_t)by * BM * K;
  const size_t baseB = (size_t)bx * BN * K;

  f32x4 acc[4][4] = {};

  const int rr = l & 15;   // fragment row (A) / col (B)
  const int kq = l >> 4;   // k-quadrant 0..3

  for (int kt = 0; kt < K; kt += BK) {
    __syncthreads();   // previous compute done before LDS overwrite
#pragma unroll
    for (int i = 0; i < 4; ++i) {
      int c = i * 256 + tid;           // chunk id: linear LDS dest = wave base + lane*16
      int row = c >> 3, cc = (c & 7) * 8;
      gload_lds16(&A[baseA + (size_t)row * K + kt + cc], &As[c * 8]);
    }
#pragma unroll
    for (int i = 0; i < 4; ++i) {
      int c = i * 256 + tid;
      int row = c >> 3, cc = (c & 7) * 8;
      gload_lds16(&B[baseB + (size_t)row * K + kt + cc], &Bs[c * 8]);
    }
    __syncthreads();   // compiler drains vmcnt(0) before barrier

#pragma unroll
    for (int kk = 0; kk < 2; ++kk) {
      bf16x8 af[4], bg[4];
#pragma unroll
      for (int m = 0; m < 4; ++m)
        af[m] = *(const bf16x8*)&As[(wr * 64 + m * 16 + rr) * BK + kk * 32 + kq * 8];
#pragma unroll
      for (int n = 0; n < 4; ++n)
        bg[n] = *(const bf16x8*)&Bs[(wc * 64 + n * 16 + rr) * BK + kk * 32 + kq * 8];
#pragma unroll
      for (int m = 0; m < 4; ++m)
#pragma unroll
        for (int n = 0; n < 4; ++n)
          acc[m][n] = __builtin_amdgcn_mfma_f32_16x16x32_bf16(af[m], bg[n], acc[m][n], 0, 0, 0);
    }
  }

  // epilogue: C[row][col] = acc + bias[col]; row=(l>>4)*4+j, col=l&15 (m89/m91 layout)
#pragma unroll
  for (int n = 0; n < 4; ++n) {
    const int col = bx * BN + wc * 64 + n * 16 + rr;
    const float bv = bias[col];
#pragma unroll
    for (int m = 0; m < 4; ++m) {
      const int row0 = by * BM + wr * 64 + m * 16 + kq * 4;
#pragma unroll
      for (int j = 0; j < 4; ++j) {
        C[(size_t)(row0 + j) * N + col] = acc[m][n][j] + bv;
      }
    }
  }
}

extern "C" void kernel_launch(void* const* d_in, const int* in_sizes, int n_in,
                              void* d_out, int out_size, void* d_ws, size_t ws_size,
                              hipStream_t stream) {
  const float* x    = (const float*)d_in[0];
  const float* wt   = (const float*)d_in[1];
  const float* bias = (const float*)d_in[2];
  float* out = (float*)d_out;

  const int N = in_sizes[2];                       // 4096
  const int K = (int)((long long)in_sizes[1] / N); // 4096
  const int M = (int)((long long)in_sizes[0] / K); // 8192

  unsigned short* xq = (unsigned short*)d_ws;           // M*K bf16 (64 MB)
  unsigned short* wq = xq + (size_t)M * K;              // N*K bf16 (32 MB)

  long long nx4 = (long long)M * K / 4;
  long long nw4 = (long long)N * K / 4;
  quant_mx<<<2048, 256, 0, stream>>>((const float4*)x,  (u16x4*)xq, nx4);
  quant_mx<<<2048, 256, 0, stream>>>((const float4*)wt, (u16x4*)wq, nw4);

  dim3 grid((M / BM) * (N / BN));  // 64*32 = 2048
  gemm_mx<<<grid, 256, 0, stream>>>(xq, wq, bias, out, M, N, K);
}

// Round 2
// 613.930 us; speedup vs baseline: 1.1036x; 1.1036x over previous
//
#include <hip/hip_runtime.h>

typedef __attribute__((ext_vector_type(8))) short bf16x8;
typedef __attribute__((ext_vector_type(4))) float f32x4;
typedef __attribute__((ext_vector_type(4))) unsigned short u16x4;

#define BM 256
#define BN 256
#define BK 64

// ---------- exact power of two: 2^e for e in [-127, 127] ----------
__device__ __forceinline__ float pow2i(int e) {
  if (e >= -126) return __uint_as_float((unsigned)(e + 127) << 23);
  return __uint_as_float(0x00400000u >> (-126 - e)); // e == -127 -> 2^-127 subnormal
}

// ---------- emulate RNE cast to e4m3fn (saturating), then dequant ----------
__device__ __forceinline__ float qdq_e4m3(float x, float inv, float scale) {
  float s = x * inv;            // exact: inv is a power of two
  float a = fabsf(s);
  int ee = (int)((__float_as_uint(a) >> 23) & 0xffu) - 127;  // floor(log2(a)) for normals
  ee = ee < -6 ? -6 : (ee > 8 ? 8 : ee);                     // clamp to e4m3 binades
  float istep = __uint_as_float((unsigned)(130 - ee) << 23); // 2^(3-ee)
  float step  = __uint_as_float((unsigned)(124 + ee) << 23); // 2^(ee-3)
  float q = rintf(a * istep) * step;  // RNE, matches jnp.round
  q = fminf(q, 448.0f);               // saturate (e4m3fn has no inf)
  return copysignf(q, s) * scale;     // exact in bf16 (<=4 significant bits * 2^k)
}

// ---------- MX quant+dequant: fp32 in, bf16 out; 8 lanes cover one 32-block ----------
__global__ void quant_mx(const float4* __restrict__ in, u16x4* __restrict__ outq,
                         long long n4) {
  long long idx = (long long)blockIdx.x * blockDim.x + threadIdx.x;
  long long stride = (long long)gridDim.x * blockDim.x;
  for (; idx < n4; idx += stride) {
    float4 v = in[idx];
    float am = fmaxf(fmaxf(fabsf(v.x), fabsf(v.y)), fmaxf(fabsf(v.z), fabsf(v.w)));
    am = fmaxf(am, __shfl_xor(am, 1));
    am = fmaxf(am, __shfl_xor(am, 2));
    am = fmaxf(am, __shfl_xor(am, 4));
    int e = (int)((__float_as_uint(am) >> 23) & 0xffu) - 135; // floor(log2)-8
    e = e < -127 ? -127 : (e > 127 ? 127 : e);
    float scale = pow2i(e);
    float inv   = pow2i(-e);
    float r0 = qdq_e4m3(v.x, inv, scale);
    float r1 = qdq_e4m3(v.y, inv, scale);
    float r2 = qdq_e4m3(v.z, inv, scale);
    float r3 = qdq_e4m3(v.w, inv, scale);
    u16x4 o;
    o[0] = (unsigned short)(__float_as_uint(r0) >> 16);
    o[1] = (unsigned short)(__float_as_uint(r1) >> 16);
    o[2] = (unsigned short)(__float_as_uint(r2) >> 16);
    o[3] = (unsigned short)(__float_as_uint(r3) >> 16);
    outq[idx] = o;
  }
}

// ---------- async global -> LDS, 16B per lane ----------
__device__ __forceinline__ void gload_lds16(const void* g, void* l) {
  __builtin_amdgcn_global_load_lds(
      (const __attribute__((address_space(1))) unsigned int*)g,
      (__attribute__((address_space(3))) unsigned int*)l, 16, 0, 0);
}

#define BAR() do { asm volatile("" ::: "memory"); \
                   __builtin_amdgcn_s_barrier();  \
                   asm volatile("" ::: "memory"); } while (0)

// ---------- 256x256 8-phase bf16 MFMA GEMM: C[M,N] = A[M,K]*B[N,K]^T + bias ----------
// T2 st-swizzle: physical LDS elem = row*64 + (col ^ ((row&7)*8)); staged via
// inverse-swizzled GLOBAL source (linear gload_lds dest), read with same XOR.
__global__ __launch_bounds__(512, 2) void gemm_mx(
    const unsigned short* __restrict__ A, const unsigned short* __restrict__ B,
    const float* __restrict__ bias, float* __restrict__ C,
    int M, int N, int K) {
  __shared__ __align__(16) unsigned short As[2][BM * BK];   // 64 KB
  __shared__ __align__(16) unsigned short Bs[2][BN * BK];   // 64 KB

  const int tid = threadIdx.x;
  const int l  = tid & 63, w = tid >> 6;
  const int wr = w >> 2, wc = w & 3;          // 2 x 4 wave grid, each wave: 128x64 out
  const int rr = l & 15, kq = l >> 4;

  const int nbx = N / BN;
  const int bid = blockIdx.x;
  const int cpx = gridDim.x >> 3;             // grid % 8 == 0 (512)
  const int swz = (bid & 7) * cpx + (bid >> 3);
  const int by = swz / nbx, bx = swz % nbx;

  const unsigned short* gA = A + (size_t)by * BM * K;
  const unsigned short* gB = B + (size_t)bx * BN * K;

  f32x4 acc[8][4] = {};

  const int swx   = (rr & 7) * 8;             // element-space XOR for reads
  const int kofs0 = (kq * 8) ^ swx;           // kk=0
  const int kofs1 = (32 + kq * 8) ^ swx;      // kk=1

  // staging: chunk ch (16B) -> LDS linear ch*16; global col16 = (ch&7) ^ (row&7)
#define STAGE(G, L, CH, KT) do {                                   \
    int _ch = (CH);                                                \
    int _row = _ch >> 3;                                           \
    int _c16 = (_ch & 7) ^ (_row & 7);                             \
    gload_lds16((G) + (size_t)_row * K + (KT) + _c16 * 8,          \
                (L) + _ch * 8);                                    \
  } while (0)

  bf16x8 af[4][2], bg[2][2];

#define READ_A(MH) _Pragma("unroll")                               \
  for (int m = 0; m < 4; ++m) {                                    \
    const int rb = (wr * 128 + ((MH) * 4 + m) * 16 + rr) * BK;     \
    af[m][0] = *(const bf16x8*)&Ac[rb + kofs0];                    \
    af[m][1] = *(const bf16x8*)&Ac[rb + kofs1];                    \
  }
#define READ_B(NH) _Pragma("unroll")                               \
  for (int n = 0; n < 2; ++n) {                                    \
    const int rb = (wc * 64 + ((NH) * 2 + n) * 16 + rr) * BK;      \
    bg[n][0] = *(const bf16x8*)&Bc[rb + kofs0];                    \
    bg[n][1] = *(const bf16x8*)&Bc[rb + kofs1];                    \
  }
#define MFMA16(MH, NH)                                             \
  asm volatile("s_waitcnt lgkmcnt(0)" ::: "memory");               \
  __builtin_amdgcn_s_setprio(1);                                   \
  _Pragma("unroll")                                                \
  for (int kk = 0; kk < 2; ++kk)                                   \
    _Pragma("unroll")                                              \
    for (int m = 0; m < 4; ++m)                                    \
      _Pragma("unroll")                                            \
      for (int n = 0; n < 2; ++n)                                  \
        acc[(MH)*4+m][(NH)*2+n] = __builtin_amdgcn_mfma_f32_16x16x32_bf16( \
            af[m][kk], bg[n][kk], acc[(MH)*4+m][(NH)*2+n], 0, 0, 0);\
  __builtin_amdgcn_s_setprio(0);

  // ---- prologue: stage tile 0 into buffer 0 (8 chunks/thread) ----
  {
    unsigned short* Ad = As[0];
    unsigned short* Bd = Bs[0];
    STAGE(gA, Ad, tid,        0); STAGE(gA, Ad, tid + 512,  0);
    STAGE(gA, Ad, tid + 1024, 0); STAGE(gA, Ad, tid + 1536, 0);
    STAGE(gB, Bd, tid,        0); STAGE(gB, Bd, tid + 512,  0);
    STAGE(gB, Bd, tid + 1024, 0); STAGE(gB, Bd, tid + 1536, 0);
  }

  const int NTK = K / BK;
  int cur = 0;
  for (int t = 0; t < NTK; ++t) {
    const bool pf = (t + 1 < NTK);
    const int ktn = (t + 1) * BK;
    unsigned short* Ac = As[cur];
    unsigned short* Bc = Bs[cur];
    unsigned short* An = As[cur ^ 1];
    unsigned short* Bn = Bs[cur ^ 1];

    // ---- phase 0: stage A(part0) for t+1; counted wait for tile t; q(0,0)
    if (pf) {
      STAGE(gA, An, tid, ktn); STAGE(gA, An, tid + 512, ktn);
      asm volatile("s_waitcnt vmcnt(2)" ::: "memory");   // drain tile t's 8, keep 2 flying
    } else {
      asm volatile("s_waitcnt vmcnt(0)" ::: "memory");
    }
    BAR();
    READ_A(0) READ_B(0)
    MFMA16(0, 0)
    BAR();

    // ---- phase 1: q(0,1); stage A(part1)
    READ_B(1)
    if (pf) { STAGE(gA, An, tid + 1024, ktn); STAGE(gA, An, tid + 1536, ktn); }
    BAR();
    MFMA16(0, 1)
    BAR();

    // ---- phase 2: q(1,0); stage B(part0)
    READ_A(1) READ_B(0)
    if (pf) { STAGE(gB, Bn, tid, ktn); STAGE(gB, Bn, tid + 512, ktn); }
    BAR();
    MFMA16(1, 0)
    BAR();

    // ---- phase 3: q(1,1); stage B(part1)
    READ_B(1)
    if (pf) { STAGE(gB, Bn, tid + 1024, ktn); STAGE(gB, Bn, tid + 1536, ktn); }
    BAR();
    MFMA16(1, 1)
    BAR();

    cur ^= 1;
  }

  // ---- epilogue: C[row][col] = acc + bias[col]; row=(l>>4)*4+j, col=l&15 ----
#pragma unroll
  for (int ni = 0; ni < 4; ++ni) {
    const int col = bx * BN + wc * 64 + ni * 16 + rr;
    const float bv = bias[col];
#pragma unroll
    for (int mi = 0; mi < 8; ++mi) {
      const int row0 = by * BM + wr * 128 + mi * 16 + kq * 4;
#pragma unroll
      for (int j = 0; j < 4; ++j) {
        C[(size_t)(row0 + j) * N + col] = acc[mi][ni][j] + bv;
      }
    }
  }
}

extern "C" void kernel_launch(void* const* d_in, const int* in_sizes, int n_in,
                              void* d_out, int out_size, void* d_ws, size_t ws_size,
                              hipStream_t stream) {
  const float* x    = (const float*)d_in[0];
  const float* wt   = (const float*)d_in[1];
  const float* bias = (const float*)d_in[2];
  float* out = (float*)d_out;

  const int N = in_sizes[2];                       // 4096
  const int K = (int)((long long)in_sizes[1] / N); // 4096
  const int M = (int)((long long)in_sizes[0] / K); // 8192

  unsigned short* xq = (unsigned short*)d_ws;      // M*K bf16 (64 MB)
  unsigned short* wq = xq + (size_t)M * K;         // N*K bf16 (32 MB)

  long long nx4 = (long long)M * K / 4;
  long long nw4 = (long long)N * K / 4;
  quant_mx<<<2048, 256, 0, stream>>>((const float4*)x,  (u16x4*)xq, nx4);
  quant_mx<<<2048, 256, 0, stream>>>((const float4*)wt, (u16x4*)wq, nw4);

  dim3 grid((M / BM) * (N / BN));                  // 32*16 = 512, %8==0
  gemm_mx<<<grid, 512, 0, stream>>>(xq, wq, bias, out, M, N, K);
}

// Round 3
// 529.366 us; speedup vs baseline: 1.2799x; 1.1597x over previous
//
#include <hip/hip_runtime.h>

typedef __attribute__((ext_vector_type(8))) short bf16x8;
typedef __attribute__((ext_vector_type(4))) float f32x4;
typedef __attribute__((ext_vector_type(4))) unsigned short u16x4;

#define BM 256
#define BN 256
#define BK 64

// ---------- exact power of two: 2^e for e in [-127, 127] ----------
__device__ __forceinline__ float pow2i(int e) {
  if (e >= -126) return __uint_as_float((unsigned)(e + 127) << 23);
  return __uint_as_float(0x00400000u >> (-126 - e)); // e == -127 -> 2^-127 subnormal
}

// ---------- emulate RNE cast to e4m3fn (saturating), then dequant ----------
__device__ __forceinline__ float qdq_e4m3(float x, float inv, float scale) {
  float s = x * inv;            // exact: inv is a power of two
  float a = fabsf(s);
  int ee = (int)((__float_as_uint(a) >> 23) & 0xffu) - 127;  // floor(log2(a)) for normals
  ee = ee < -6 ? -6 : (ee > 8 ? 8 : ee);                     // clamp to e4m3 binades
  float istep = __uint_as_float((unsigned)(130 - ee) << 23); // 2^(3-ee)
  float step  = __uint_as_float((unsigned)(124 + ee) << 23); // 2^(ee-3)
  float q = rintf(a * istep) * step;  // RNE, matches jnp.round
  q = fminf(q, 448.0f);               // saturate (e4m3fn has no inf)
  return copysignf(q, s) * scale;     // exact in bf16 (<=4 significant bits * 2^k)
}

__device__ __forceinline__ u16x4 qdq_pack(float4 v) {
  float am = fmaxf(fmaxf(fabsf(v.x), fabsf(v.y)), fmaxf(fabsf(v.z), fabsf(v.w)));
  am = fmaxf(am, __shfl_xor(am, 1));
  am = fmaxf(am, __shfl_xor(am, 2));
  am = fmaxf(am, __shfl_xor(am, 4));
  int e = (int)((__float_as_uint(am) >> 23) & 0xffu) - 135; // floor(log2)-8
  e = e < -127 ? -127 : (e > 127 ? 127 : e);
  float scale = pow2i(e);
  float inv   = pow2i(-e);
  u16x4 o;
  o[0] = (unsigned short)(__float_as_uint(qdq_e4m3(v.x, inv, scale)) >> 16);
  o[1] = (unsigned short)(__float_as_uint(qdq_e4m3(v.y, inv, scale)) >> 16);
  o[2] = (unsigned short)(__float_as_uint(qdq_e4m3(v.z, inv, scale)) >> 16);
  o[3] = (unsigned short)(__float_as_uint(qdq_e4m3(v.w, inv, scale)) >> 16);
  return o;
}

// ---------- MX quant+dequant: fp32 in, bf16 out; 8 lanes cover one 32-block ----------
// 4 independent chunks per thread (ILP); grid sized so 4*stride covers n4.
__global__ void quant_mx(const float4* __restrict__ in, u16x4* __restrict__ outq,
                         long long n4) {
  const long long base = (long long)blockIdx.x * blockDim.x + threadIdx.x;
  const long long stride = (long long)gridDim.x * blockDim.x;
  const long long i0 = base, i1 = base + stride, i2 = base + 2 * stride, i3 = base + 3 * stride;
  float4 v0, v1, v2, v3;
  if (i0 < n4) v0 = in[i0];
  if (i1 < n4) v1 = in[i1];
  if (i2 < n4) v2 = in[i2];
  if (i3 < n4) v3 = in[i3];
  u16x4 o0, o1, o2, o3;
  if (i0 < n4) o0 = qdq_pack(v0);
  if (i1 < n4) o1 = qdq_pack(v1);
  if (i2 < n4) o2 = qdq_pack(v2);
  if (i3 < n4) o3 = qdq_pack(v3);
  if (i0 < n4) outq[i0] = o0;
  if (i1 < n4) outq[i1] = o1;
  if (i2 < n4) outq[i2] = o2;
  if (i3 < n4) outq[i3] = o3;
}

// ---------- async global -> LDS, 16B per lane ----------
__device__ __forceinline__ void gload_lds16(const void* g, void* l) {
  __builtin_amdgcn_global_load_lds(
      (const __attribute__((address_space(1))) unsigned int*)g,
      (__attribute__((address_space(3))) unsigned int*)l, 16, 0, 0);
}

#define BAR() do { asm volatile("" ::: "memory"); \
                   __builtin_amdgcn_s_barrier();  \
                   asm volatile("" ::: "memory"); } while (0)
#define WAIT_LGKM() asm volatile("s_waitcnt lgkmcnt(0)" ::: "memory")
#define WAIT_VM0()  asm volatile("s_waitcnt vmcnt(0)" ::: "memory")

// ---------- 256x256 8-phase bf16 MFMA GEMM: C[M,N] = A[M,K]*B[N,K]^T + bias ----------
// T2 st-swizzle: physical LDS elem = row*64 + (col ^ ((row&7)*8)); staged via
// inverse-swizzled GLOBAL source (linear gload_lds dest), read with same XOR.
__global__ __launch_bounds__(512, 2) void gemm_mx(
    const unsigned short* __restrict__ A, const unsigned short* __restrict__ B,
    const float* __restrict__ bias, float* __restrict__ C,
    int M, int N, int K) {
  __shared__ __align__(16) unsigned short As[2][BM * BK];   // 64 KB
  __shared__ __align__(16) unsigned short Bs[2][BN * BK];   // 64 KB

  const int tid = threadIdx.x;
  const int l  = tid & 63, w = tid >> 6;
  const int wr = w >> 2, wc = w & 3;          // 2 x 4 wave grid, each wave: 128x64 out
  const int rr = l & 15, kq = l >> 4;

  const int nbx = N / BN;
  const int bid = blockIdx.x;
  const int cpx = gridDim.x >> 3;             // grid % 8 == 0 (512)
  const int swz = (bid & 7) * cpx + (bid >> 3);
  const int by = swz / nbx, bx = swz % nbx;

  const unsigned short* gA = A + (size_t)by * BM * K;
  const unsigned short* gB = B + (size_t)bx * BN * K;

  f32x4 acc[8][4] = {};

  const int swx   = (rr & 7) * 8;             // element-space XOR for reads
  const int kofs0 = (kq * 8) ^ swx;           // kk=0
  const int kofs1 = (32 + kq * 8) ^ swx;      // kk=1

  // staging: chunk ch (16B) -> LDS linear ch*16; global col16 = (ch&7) ^ (row&7)
#define STAGE(G, L, CH, KT) do {                                   \
    int _ch = (CH);                                                \
    int _row = _ch >> 3;                                           \
    int _c16 = (_ch & 7) ^ (_row & 7);                             \
    gload_lds16((G) + (size_t)_row * K + (KT) + _c16 * 8,          \
                (L) + _ch * 8);                                    \
  } while (0)

  bf16x8 af[4][2], bg[4][2];   // bg holds ALL 4 n-frags (both halves) resident

#define READ_A(MH) _Pragma("unroll")                               \
  for (int m = 0; m < 4; ++m) {                                    \
    const int rb = (wr * 128 + ((MH) * 4 + m) * 16 + rr) * BK;     \
    af[m][0] = *(const bf16x8*)&Ac[rb + kofs0];                    \
    af[m][1] = *(const bf16x8*)&Ac[rb + kofs1];                    \
  }
#define READ_B(NH) _Pragma("unroll")                               \
  for (int n = 0; n < 2; ++n) {                                    \
    const int rb = (wc * 64 + ((NH) * 2 + n) * 16 + rr) * BK;      \
    bg[(NH) * 2 + n][0] = *(const bf16x8*)&Bc[rb + kofs0];         \
    bg[(NH) * 2 + n][1] = *(const bf16x8*)&Bc[rb + kofs1];         \
  }
#define MFMA16(MH, NH)                                             \
  __builtin_amdgcn_s_setprio(1);                                   \
  _Pragma("unroll")                                                \
  for (int kk = 0; kk < 2; ++kk)                                   \
    _Pragma("unroll")                                              \
    for (int m = 0; m < 4; ++m)                                    \
      _Pragma("unroll")                                            \
      for (int n = 0; n < 2; ++n)                                  \
        acc[(MH)*4+m][(NH)*2+n] = __builtin_amdgcn_mfma_f32_16x16x32_bf16( \
            af[m][kk], bg[(NH)*2+n][kk], acc[(MH)*4+m][(NH)*2+n], 0, 0, 0);\
  __builtin_amdgcn_s_setprio(0);

  // ---- prologue: stage tile 0 into buffer 0 (8 chunks/thread) ----
  {
    unsigned short* Ad = As[0];
    unsigned short* Bd = Bs[0];
    STAGE(gA, Ad, tid,        0); STAGE(gA, Ad, tid + 512,  0);
    STAGE(gA, Ad, tid + 1024, 0); STAGE(gA, Ad, tid + 1536, 0);
    STAGE(gB, Bd, tid,        0); STAGE(gB, Bd, tid + 512,  0);
    STAGE(gB, Bd, tid + 1024, 0); STAGE(gB, Bd, tid + 1536, 0);
    WAIT_VM0();
    BAR();
  }

  const int NTK = K / BK;
  int cur = 0;
  for (int t = 0; t < NTK; ++t) {
    const bool pf = (t + 1 < NTK);
    const int ktn = (t + 1) * BK;
    unsigned short* Ac = As[cur];
    unsigned short* Bc = Bs[cur];
    unsigned short* An = As[cur ^ 1];
    unsigned short* Bn = Bs[cur ^ 1];

    // ---- phase 0: q(0,0); issue ALL A stages for t+1 (max latency cover)
    READ_A(0) READ_B(0)
    if (pf) {
      STAGE(gA, An, tid,        ktn); STAGE(gA, An, tid + 512,  ktn);
      STAGE(gA, An, tid + 1024, ktn); STAGE(gA, An, tid + 1536, ktn);
    }
    BAR();
    WAIT_LGKM();
    MFMA16(0, 0)
    BAR();

    // ---- phase 1: q(0,1); issue ALL B stages for t+1
    READ_B(1)
    if (pf) {
      STAGE(gB, Bn, tid,        ktn); STAGE(gB, Bn, tid + 512,  ktn);
      STAGE(gB, Bn, tid + 1024, ktn); STAGE(gB, Bn, tid + 1536, ktn);
    }
    BAR();
    WAIT_LGKM();
    MFMA16(0, 1)
    BAR();

    // ---- phase 2: q(1,1)  (bg half-1 still resident)
    READ_A(1)
    BAR();
    WAIT_LGKM();
    MFMA16(1, 1)
    BAR();

    // ---- phase 3: q(1,0)  (bg half-0 still resident; no ds_read)
    MFMA16(1, 0)
    WAIT_VM0();    // drain t+1's stages: issued 2.5-3.5 phases ago -> nearly free
    BAR();

    cur ^= 1;
  }

  // ---- epilogue: C[row][col] = acc + bias[col]; row=(l>>4)*4+j, col=l&15 ----
#pragma unroll
  for (int ni = 0; ni < 4; ++ni) {
    const int col = bx * BN + wc * 64 + ni * 16 + rr;
    const float bv = bias[col];
#pragma unroll
    for (int mi = 0; mi < 8; ++mi) {
      const int row0 = by * BM + wr * 128 + mi * 16 + kq * 4;
#pragma unroll
      for (int j = 0; j < 4; ++j) {
        C[(size_t)(row0 + j) * N + col] = acc[mi][ni][j] + bv;
      }
    }
  }
}

extern "C" void kernel_launch(void* const* d_in, const int* in_sizes, int n_in,
                              void* d_out, int out_size, void* d_ws, size_t ws_size,
                              hipStream_t stream) {
  const float* x    = (const float*)d_in[0];
  const float* wt   = (const float*)d_in[1];
  const float* bias = (const float*)d_in[2];
  float* out = (float*)d_out;

  const int N = in_sizes[2];                       // 4096
  const int K = (int)((long long)in_sizes[1] / N); // 4096
  const int M = (int)((long long)in_sizes[0] / K); // 8192

  unsigned short* xq = (unsigned short*)d_ws;      // M*K bf16 (64 MB)
  unsigned short* wq = xq + (size_t)M * K;         // N*K bf16 (32 MB)

  long long nx4 = (long long)M * K / 4;
  long long nw4 = (long long)N * K / 4;
  int gx = (int)((nx4 + 4LL * 256 - 1) / (4LL * 256));  // 4 chunks/thread
  int gw = (int)((nw4 + 4LL * 256 - 1) / (4LL * 256));
  quant_mx<<<gx, 256, 0, stream>>>((const float4*)x,  (u16x4*)xq, nx4);
  quant_mx<<<gw, 256, 0, stream>>>((const float4*)wt, (u16x4*)wq, nw4);

  dim3 grid((M / BM) * (N / BN));                  // 32*16 = 512, %8==0
  gemm_mx<<<grid, 512, 0, stream>>>(xq, wq, bias, out, M, N, K);
}